// Round 1
// baseline (605.579 us; speedup 1.0000x reference)
//
#include <hip/hip_runtime.h>

// ConvolutionalSelfAttention: B=8, C=512, N=4096 (64x64), D=64
// out[b,c,n] = gamma * sum_i hv[b,c,i] * softmax_i(f[.,i]. g[.,j])[i,j=n] + skip[b,c,n]
// Keys   K = f = Wq @ skip   [B,N,D]
// Query  Q = g = Wk @ skip   [B,N,D]
// Values V = hv = Wv @ res   [B,C,N]
//
// ws layout (needs ~41 MiB):
//  [0,4M)    Kmat bf16 [B][N][64]
//  [4M,8M)   Qmat bf16 [B][N][64]
//  [8M,40M)  Vmat bf16 [B][512][N]
//  [40M,+128K)  m_ws  f32 [B][N]
//  [+128K,+256K) sc_ws f32 [B][N]   (= gamma / l_j)
//  then Wq/Wk/Wv bf16 copies

#define B_ 8
#define C_ 512
#define N_ 4096
#define D_ 64

typedef __bf16 bf16x8 __attribute__((ext_vector_type(8)));
typedef float  f32x16 __attribute__((ext_vector_type(16)));

#define MFMA32 __builtin_amdgcn_mfma_f32_32x32x16_bf16

__device__ __forceinline__ unsigned pk_bf16(float a, float b) {
  unsigned r;
  asm("v_cvt_pk_bf16_f32 %0, %1, %2" : "=v"(r) : "v"(a), "v"(b));
  return r;
}

__device__ __forceinline__ bf16x8 ldg_frag(const unsigned short* p) {
  uint4 u = *(const uint4*)p;
  return __builtin_bit_cast(bf16x8, u);
}
__device__ __forceinline__ bf16x8 lds_frag(const unsigned char* p) {
  uint4 u = *(const uint4*)p;
  return __builtin_bit_cast(bf16x8, u);
}

// ---- weight f32 -> bf16 conversion ----
__global__ void cvt_w(const float* __restrict__ src, unsigned short* __restrict__ dst, int n) {
  int i = (blockIdx.x * blockDim.x + threadIdx.x) * 2;
  if (i + 1 < n + 1) {
    unsigned v = pk_bf16(src[i], src[i + 1]);
    *(unsigned*)(dst + i) = v;
  }
}

// Transpose-stage a [64 c][64 i] f32 global tile (row stride N_) into
// LDS Xt[i][c] bf16 (128B rows), XOR-swizzled by ((i&7)<<4).
__device__ __forceinline__ void stage64(const float* __restrict__ src,
                                        unsigned char* __restrict__ dst, int t) {
  int si = (t & 15) << 2;   // i column base (4 per thread)
  int cl = (t >> 4) << 1;   // c row pair base
#pragma unroll
  for (int p = 0; p < 2; ++p) {
    int c = cl + p * 32;
    const float* r0 = src + (size_t)c * N_ + si;
    float4 a0 = *(const float4*)r0;
    float4 a1 = *(const float4*)(r0 + N_);
    const float* f0 = (const float*)&a0;
    const float* f1 = (const float*)&a1;
    int cb = c << 1;
#pragma unroll
    for (int k = 0; k < 4; ++k) {
      int ii = si + k;
      unsigned v = pk_bf16(f0[k], f1[k]);  // lo=c, hi=c+1
      *(unsigned*)(dst + (((ii << 7) + cb) ^ ((ii & 7) << 4))) = v;
    }
  }
}

// ---- K/Q projections: OutT[d][i] tiles; store Kmat/Qmat[b][i][d] ----
__global__ __launch_bounds__(256, 2) void fg_proj(
    const float* __restrict__ skip,
    const unsigned short* __restrict__ Wqb, const unsigned short* __restrict__ Wkb,
    unsigned short* __restrict__ Kmat, unsigned short* __restrict__ Qmat) {
  __shared__ __align__(16) unsigned char Xs[2][8192];
  int blk = blockIdx.x, b = blk & 7, i0 = (blk >> 3) << 6;
  int t = threadIdx.x, lane = t & 63, w = t >> 6, hi = lane >> 5, l5 = lane & 31;
  int dh = w >> 1, ih = w & 1;
  f32x16 ka, qa;
#pragma unroll
  for (int r = 0; r < 16; ++r) { ka[r] = 0.f; qa[r] = 0.f; }
  int il = (ih << 5) + l5;   // i within tile (B-frag n)
  int dr = (dh << 5) + l5;   // d row (A-frag m)
#pragma unroll 1
  for (int kk = 0; kk < 8; ++kk) {
    int c0 = kk << 6;
    unsigned char* buf = Xs[kk & 1];
    stage64(skip + ((size_t)(b * C_ + c0)) * N_ + i0, buf, t);
    __syncthreads();
#pragma unroll
    for (int ks = 0; ks < 4; ++ks) {
      int co = (ks << 4) + (hi << 3);
      bf16x8 aq = ldg_frag(Wqb + (size_t)dr * C_ + c0 + co);
      bf16x8 ak = ldg_frag(Wkb + (size_t)dr * C_ + c0 + co);
      bf16x8 bx = lds_frag(buf + (((il << 7) + (co << 1)) ^ ((il & 7) << 4)));
      ka = MFMA32(aq, bx, ka, 0, 0, 0);
      qa = MFMA32(ak, bx, qa, 0, 0, 0);
    }
  }
  // D layout: col = i (lane), row = d = (r&3)+8*(r>>2)+4*hi
  size_t rowb = ((size_t)b * N_ + i0 + il) * D_ + (dh << 5);
#pragma unroll
  for (int q = 0; q < 4; ++q) {
    int dq = (q << 3) + (hi << 2);
    uint2 v;
    v.x = pk_bf16(ka[q * 4 + 0], ka[q * 4 + 1]);
    v.y = pk_bf16(ka[q * 4 + 2], ka[q * 4 + 3]);
    *(uint2*)(Kmat + rowb + dq) = v;
    v.x = pk_bf16(qa[q * 4 + 0], qa[q * 4 + 1]);
    v.y = pk_bf16(qa[q * 4 + 2], qa[q * 4 + 3]);
    *(uint2*)(Qmat + rowb + dq) = v;
  }
}

// ---- V projection: block [i 64][c 512]; store Vmat[b][c][i] ----
__global__ __launch_bounds__(256, 2) void hv_proj(
    const float* __restrict__ res, const unsigned short* __restrict__ Wvb,
    unsigned short* __restrict__ Vmat) {
  __shared__ __align__(16) unsigned char Xs[2][8192];
  int blk = blockIdx.x, b = blk & 7, i0 = (blk >> 3) << 6;
  int t = threadIdx.x, lane = t & 63, w = t >> 6, hi = lane >> 5, l5 = lane & 31;
  int cw = w << 7;
  f32x16 acc[2][4];
#pragma unroll
  for (int a = 0; a < 2; ++a)
#pragma unroll
    for (int c = 0; c < 4; ++c)
#pragma unroll
      for (int r = 0; r < 16; ++r) acc[a][c][r] = 0.f;
#pragma unroll 1
  for (int kk = 0; kk < 8; ++kk) {
    int c0 = kk << 6;
    unsigned char* buf = Xs[kk & 1];
    stage64(res + ((size_t)(b * C_ + c0)) * N_ + i0, buf, t);
    __syncthreads();
#pragma unroll
    for (int ks = 0; ks < 4; ++ks) {
      int co = (ks << 4) + (hi << 3);
      bf16x8 a0 = lds_frag(buf + (((l5 << 7) + (co << 1)) ^ ((l5 & 7) << 4)));
      bf16x8 a1 = lds_frag(buf + ((((32 + l5) << 7) + (co << 1)) ^ ((l5 & 7) << 4)));
#pragma unroll
      for (int ct = 0; ct < 4; ++ct) {
        bf16x8 bv = ldg_frag(Wvb + (size_t)(cw + (ct << 5) + l5) * C_ + c0 + co);
        acc[0][ct] = MFMA32(a0, bv, acc[0][ct], 0, 0, 0);
        acc[1][ct] = MFMA32(a1, bv, acc[1][ct], 0, 0, 0);
      }
    }
  }
  // D layout: col = c (lane), row = i
#pragma unroll
  for (int ihh = 0; ihh < 2; ++ihh)
#pragma unroll
    for (int ct = 0; ct < 4; ++ct) {
      int c = cw + (ct << 5) + l5;
      unsigned short* vp = Vmat + ((size_t)b * C_ + c) * N_ + i0 + (ihh << 5);
#pragma unroll
      for (int q = 0; q < 4; ++q) {
        int iq = (q << 3) + (hi << 2);
        uint2 v;
        v.x = pk_bf16(acc[ihh][ct][q * 4 + 0], acc[ihh][ct][q * 4 + 1]);
        v.y = pk_bf16(acc[ihh][ct][q * 4 + 2], acc[ihh][ct][q * 4 + 3]);
        *(uint2*)(vp + iq) = v;
      }
    }
}

__device__ __forceinline__ void online_upd(float& m, float& l, const f32x16& s) {
  float tm = s[0];
#pragma unroll
  for (int r = 1; r < 16; ++r) tm = fmaxf(tm, s[r]);
  float nm = fmaxf(m, tm);
  float acc = l * __expf(m - nm);
#pragma unroll
  for (int r = 0; r < 16; ++r) acc += __expf(s[r] - nm);
  m = nm;
  l = acc;
}

// ---- per-column softmax stats: m_j, gamma/l_j ----
__global__ __launch_bounds__(256) void stats_k(
    const unsigned short* __restrict__ Kmat, const unsigned short* __restrict__ Qmat,
    const float* __restrict__ gamma, float* __restrict__ m_ws, float* __restrict__ sc_ws) {
  __shared__ float mr[4][64];
  __shared__ float lr[4][64];
  int blk = blockIdx.x, b = blk & 7, j0 = (blk >> 3) << 6;
  int t = threadIdx.x, lane = t & 63, w = t >> 6, hi = lane >> 5, l5 = lane & 31;
  bf16x8 qf[2][4];
#pragma unroll
  for (int jh = 0; jh < 2; ++jh)
#pragma unroll
    for (int ks = 0; ks < 4; ++ks)
      qf[jh][ks] = ldg_frag(Qmat + ((size_t)b * N_ + j0 + (jh << 5) + l5) * D_ + (ks << 4) + (hi << 3));
  float m0 = -INFINITY, l0 = 0.f, m1 = -INFINITY, l1 = 0.f;
  for (int it = w; it < 128; it += 4) {
    const unsigned short* kp = Kmat + ((size_t)b * N_ + (it << 5) + l5) * D_ + (hi << 3);
    f32x16 s0, s1;
#pragma unroll
    for (int r = 0; r < 16; ++r) { s0[r] = 0.f; s1[r] = 0.f; }
#pragma unroll
    for (int ks = 0; ks < 4; ++ks) {
      bf16x8 a = ldg_frag(kp + (ks << 4));
      s0 = MFMA32(a, qf[0][ks], s0, 0, 0, 0);
      s1 = MFMA32(a, qf[1][ks], s1, 0, 0, 0);
    }
    online_upd(m0, l0, s0);
    online_upd(m1, l1, s1);
  }
  // combine lane pair (l, l^32): same j, complementary rows
  {
    float om = __shfl_xor(m0, 32);
    float ol = __shfl_xor(l0, 32);
    float nm = fmaxf(m0, om);
    l0 = l0 * __expf(m0 - nm) + ol * __expf(om - nm);
    m0 = nm;
    om = __shfl_xor(m1, 32);
    ol = __shfl_xor(l1, 32);
    nm = fmaxf(m1, om);
    l1 = l1 * __expf(m1 - nm) + ol * __expf(om - nm);
    m1 = nm;
  }
  mr[w][lane] = (lane < 32) ? m0 : m1;
  lr[w][lane] = (lane < 32) ? l0 : l1;
  __syncthreads();
  if (t < 64) {
    float M = mr[0][t];
#pragma unroll
    for (int ww = 1; ww < 4; ++ww) M = fmaxf(M, mr[ww][t]);
    float L = 0.f;
#pragma unroll
    for (int ww = 0; ww < 4; ++ww) L += lr[ww][t] * __expf(mr[ww][t] - M);
    m_ws[(size_t)b * N_ + j0 + t] = M;
    sc_ws[(size_t)b * N_ + j0 + t] = gamma[0] / L;
  }
}

// ---- main attention: per (b, 64-j tile); O[j][c] = sum_i P[i][j] V[c][i] ----
__global__ __launch_bounds__(256, 2) void attn_pv(
    const unsigned short* __restrict__ Kmat, const unsigned short* __restrict__ Qmat,
    const unsigned short* __restrict__ Vmat, const float* __restrict__ m_ws,
    const float* __restrict__ sc_ws, const float* __restrict__ skip,
    float* __restrict__ out) {
  __shared__ __align__(16) unsigned char P[2][8192];  // [64 j][64 i] bf16, swizzled
  int blk = blockIdx.x, b = blk & 7, j0 = (blk >> 3) << 6;
  int t = threadIdx.x, lane = t & 63, w = t >> 6, hi = lane >> 5, l5 = lane & 31;
  int ih = w >> 1, jh = w & 1, cw = w << 7;
  // Q fragments for this wave's S quadrant (fixed all loop)
  bf16x8 qf[4];
#pragma unroll
  for (int ks = 0; ks < 4; ++ks)
    qf[ks] = ldg_frag(Qmat + ((size_t)b * N_ + j0 + (jh << 5) + l5) * D_ + (ks << 4) + (hi << 3));
  float mj = m_ws[(size_t)b * N_ + j0 + (jh << 5) + l5];
  float scj = sc_ws[(size_t)b * N_ + j0 + (jh << 5) + l5];
  f32x16 acc[2][4];
#pragma unroll
  for (int a = 0; a < 2; ++a)
#pragma unroll
    for (int c = 0; c < 4; ++c)
#pragma unroll
      for (int r = 0; r < 16; ++r) acc[a][c][r] = 0.f;
  int jw = (jh << 5) + l5;
  unsigned wbase = jw << 7;
  unsigned wswz = (jw & 7) << 4;
#pragma unroll 1
  for (int it = 0; it < 64; ++it) {
    int ib = it << 6;
    unsigned char* pb = P[it & 1];
    // --- S quadrant: rows i = ib + ih*32 + crow, cols j = j0 + jh*32 + lane ---
    const unsigned short* kp =
        Kmat + ((size_t)b * N_ + ib + (ih << 5) + l5) * D_ + (hi << 3);
    f32x16 s;
#pragma unroll
    for (int r = 0; r < 16; ++r) s[r] = 0.f;
#pragma unroll
    for (int ks = 0; ks < 4; ++ks) {
      bf16x8 a = ldg_frag(kp + (ks << 4));
      s = MFMA32(a, qf[ks], s, 0, 0, 0);
    }
    // P = exp(s - m_j) * (gamma / l_j), packed bf16 pairs -> LDS
#pragma unroll
    for (int pr = 0; pr < 8; ++pr) {
      float e0 = __expf(s[2 * pr] - mj) * scj;
      float e1 = __expf(s[2 * pr + 1] - mj) * scj;
      unsigned v = pk_bf16(e0, e1);
      int il = (ih << 5) + ((pr & 1) << 1) + ((pr >> 1) << 3) + (hi << 2);
      *(unsigned*)(pb + ((wbase + (il << 1)) ^ wswz)) = v;
    }
    __syncthreads();
    // --- PV: this wave's 128-c slice, both j halves ---
    const unsigned short* vp = Vmat + ((size_t)b * C_ + cw + l5) * N_ + ib + (hi << 3);
#pragma unroll
    for (int ks = 0; ks < 4; ++ks) {
      int iob = ((ks << 4) + (hi << 3)) << 1;
      bf16x8 pa0 = lds_frag(pb + (((l5 << 7) + iob) ^ ((l5 & 7) << 4)));
      bf16x8 pa1 = lds_frag(pb + ((((32 + l5) << 7) + iob) ^ ((l5 & 7) << 4)));
#pragma unroll
      for (int ct = 0; ct < 4; ++ct) {
        bf16x8 bv = ldg_frag(vp + (size_t)(ct << 5) * N_ + (ks << 4));
        acc[0][ct] = MFMA32(pa0, bv, acc[0][ct], 0, 0, 0);
        acc[1][ct] = MFMA32(pa1, bv, acc[1][ct], 0, 0, 0);
      }
    }
    // double-buffered P: no second barrier needed
  }
  // epilogue: out = acc + skip (gamma/l already folded into P)
#pragma unroll
  for (int jt = 0; jt < 2; ++jt)
#pragma unroll
    for (int ct = 0; ct < 4; ++ct) {
      int c = cw + (ct << 5) + l5;
      size_t base = ((size_t)b * C_ + c) * N_ + j0 + (jt << 5) + (hi << 2);
#pragma unroll
      for (int q = 0; q < 4; ++q) {
        float4 s4 = *(const float4*)(skip + base + (q << 3));
        float4 o4;
        o4.x = acc[jt][ct][q * 4 + 0] + s4.x;
        o4.y = acc[jt][ct][q * 4 + 1] + s4.y;
        o4.z = acc[jt][ct][q * 4 + 2] + s4.z;
        o4.w = acc[jt][ct][q * 4 + 3] + s4.w;
        *(float4*)(out + base + (q << 3)) = o4;
      }
    }
}

extern "C" void kernel_launch(void* const* d_in, const int* in_sizes, int n_in,
                              void* d_out, int out_size, void* d_ws, size_t ws_size,
                              hipStream_t stream) {
  (void)in_sizes; (void)n_in; (void)out_size; (void)ws_size;
  const float* skip = (const float*)d_in[0];
  const float* res = (const float*)d_in[1];
  const float* Wq = (const float*)d_in[2];
  const float* Wk = (const float*)d_in[3];
  const float* Wv = (const float*)d_in[4];
  const float* gamma = (const float*)d_in[5];
  float* out = (float*)d_out;
  char* ws = (char*)d_ws;

  unsigned short* Kmat = (unsigned short*)(ws);
  unsigned short* Qmat = (unsigned short*)(ws + (4ull << 20));
  unsigned short* Vmat = (unsigned short*)(ws + (8ull << 20));
  float* m_ws = (float*)(ws + (40ull << 20));
  float* sc_ws = (float*)(ws + (40ull << 20) + (128ull << 10));
  unsigned short* Wqb = (unsigned short*)(ws + (40ull << 20) + (256ull << 10));
  unsigned short* Wkb = Wqb + 64 * 512;
  unsigned short* Wvb = Wkb + 64 * 512;

  cvt_w<<<64, 256, 0, stream>>>(Wq, Wqb, 64 * 512);
  cvt_w<<<64, 256, 0, stream>>>(Wk, Wkb, 64 * 512);
  cvt_w<<<512, 256, 0, stream>>>(Wv, Wvb, 512 * 512);
  fg_proj<<<512, 256, 0, stream>>>(skip, Wqb, Wkb, Kmat, Qmat);
  hv_proj<<<512, 256, 0, stream>>>(res, Wvb, Vmat);
  stats_k<<<512, 256, 0, stream>>>(Kmat, Qmat, gamma, m_ws, sc_ws);
  attn_pv<<<512, 256, 0, stream>>>(Kmat, Qmat, Vmat, m_ws, sc_ws, skip, out);
}